// Round 12
// baseline (171.319 us; speedup 1.0000x reference)
//
#include <hip/hip_runtime.h>
#include <hip/hip_fp16.h>
#include <math.h>

// GCN, R22: R21 fetch-shape experiment (4 lanes/node x uint4 -> 16 rows in
// flight per wave-wide load instruction, half the load instrs, half the grid)
// with the GATHER8Q UB FIXED: explicit named accumulators per half2 word, no
// pointer arithmetic over locals (R21's `&a0` indexing corrupted a1..a7).
// Build path byte-identical to R20. Discriminates per-CU miss capacity (null)
// vs per-wave load-slot limit (-25..30%).
// u rows fp16, stride 32 halves = one 64B line. eb packed (src<<8)|(dst&255).

#define TPB 256
#define BSH 8                 // 256 nodes per bucket
#define BNODES 256
#define MAXBUCK 512
#define CH 4096               // edges per partition block
#define CAPSH 13              // slab capacity 8192 entries/bucket
#define CAP (1 << CAPSH)

// partition edges into per-bucket slabs; bcursor RELATIVE (memset 0).
// block 0 also zeroes the dummy row n of u1h/u2h.
__global__ void k_part(const int* __restrict__ src, const int* __restrict__ dst,
                       int* __restrict__ bcursor, int* __restrict__ eb,
                       __half* __restrict__ u1h, __half* __restrict__ u2h,
                       int E, int n, int nbuck) {
    __shared__ int lh[MAXBUCK];
    __shared__ int lbase[MAXBUCK];
    int t = threadIdx.x;
    if (blockIdx.x == 0 && t < 32) {
        u1h[(size_t)n * 32 + t] = __float2half_rn(0.f);
        u2h[(size_t)n * 32 + t] = __float2half_rn(0.f);
    }
    int chunk0 = blockIdx.x * CH;
    int end = min(chunk0 + CH, E);
    const int4* dst4 = (const int4*)dst;
    const int4* src4 = (const int4*)src;
    for (int i = t; i < nbuck; i += TPB) lh[i] = 0;
    __syncthreads();
    for (int e4 = chunk0 / 4 + t; e4 * 4 < end; e4 += TPB) {
        int base = e4 * 4;
        int4 d = dst4[e4];
        if (base + 0 < end) atomicAdd(&lh[d.x >> BSH], 1);
        if (base + 1 < end) atomicAdd(&lh[d.y >> BSH], 1);
        if (base + 2 < end) atomicAdd(&lh[d.z >> BSH], 1);
        if (base + 3 < end) atomicAdd(&lh[d.w >> BSH], 1);
    }
    __syncthreads();
    for (int i = t; i < nbuck; i += TPB) {
        int c = lh[i];
        lbase[i] = c ? atomicAdd(&bcursor[i], c) : 0;
        lh[i] = 0;
    }
    __syncthreads();
    for (int e4 = chunk0 / 4 + t; e4 * 4 < end; e4 += TPB) {
        int base = e4 * 4;
        int4 d = dst4[e4];
        int4 s = src4[e4];
        #define PUT(c, sv) if (base + c < end) { \
            int b = (d.sv) >> BSH; \
            int r = lbase[b] + atomicAdd(&lh[b], 1); \
            if (r < CAP) \
                eb[((size_t)b << CAPSH) + r] = ((s.sv) << BSH) | ((d.sv) & (BNODES - 1)); }
        PUT(0, x) PUT(1, y) PUT(2, z) PUT(3, w)
        #undef PUT
    }
}

// per bucket: LDS hist -> wave-shfl pad-scan -> counting scatter into PADDED
// csr segments (8-aligned, pads = node id n -> zero row) -> transform-first
// u1h rows: (x@W1)*dinv in fp16.
__global__ void k_bucket(const int* __restrict__ eb, const int* __restrict__ bcursor,
                         const float* __restrict__ x, const float* __restrict__ W1,
                         int* __restrict__ csr, int* __restrict__ row_start,
                         int* __restrict__ cnt8, float* __restrict__ dinv,
                         __half* __restrict__ u1h, int n) {
    __shared__ int lcnt[BNODES];
    __shared__ int wsum[4];
    __shared__ float ldinv[BNODES];
    __shared__ float xs[BNODES * 18];
    int b = blockIdx.x;
    int t = threadIdx.x;
    int node0 = b << BSH;
    int beg = b << CAPSH;
    int end = beg + min(bcursor[b], CAP);
    lcnt[t] = 0;
    __syncthreads();
    for (int i = beg + t; i < end; i += TPB)
        atomicAdd(&lcnt[eb[i] & (BNODES - 1)], 1);
    __syncthreads();
    int v = lcnt[t];
    int pad = (v + 7) & ~7;          // 8-aligned segments for 8-wide agg
    int lane = t & 63, wv = t >> 6;
    int val = pad;
#pragma unroll
    for (int off = 1; off < 64; off <<= 1) {
        int y = __shfl_up(val, off, 64);
        if (lane >= off) val += y;
    }
    if (lane == 63) wsum[wv] = val;
    __syncthreads();
    int add = 0;
#pragma unroll
    for (int w2 = 0; w2 < 4; ++w2) add += (w2 < wv) ? wsum[w2] : 0;
    int pexcl = val + add - pad;     // exclusive padded prefix
    int node = node0 + t;
    float dv = rsqrtf(1.0f + (float)v);
    ldinv[t] = dv;
    if (node < n) {
        row_start[node] = beg + pexcl;
        cnt8[node] = pad >> 3;
        dinv[node] = dv;
    }
    lcnt[t] = pexcl;
    __syncthreads();
    for (int i = beg + t; i < end; i += TPB) {
        int e = eb[i];
        int p = atomicAdd(&lcnt[e & (BNODES - 1)], 1);
        csr[beg + p] = e >> BSH;
    }
    for (int p = v; p < pad; ++p) csr[beg + pexcl + p] = n;
    // ---- transform-first: u1h[node][f] = ((x[node] @ W1)[f]) * dinv[node] ----
    int nn = min(BNODES, n - node0);
    const float* xb = x + (size_t)node0 * 18;
    int tot18 = nn * 18;
    for (int i = t; i < tot18; i += TPB) xs[i] = xb[i];
    __syncthreads();
    int f = t & 31, g = t >> 5;
    float w1r[18];
#pragma unroll
    for (int k = 0; k < 18; ++k) w1r[k] = W1[k * 32 + f];
    __half* ub = u1h + (size_t)node0 * 32;
    for (int nl = g; nl < nn; nl += 8) {
        const float* rp = &xs[nl * 18];
        float a = 0.f;
#pragma unroll
        for (int k = 0; k < 18; ++k) a = fmaf(rp[k], w1r[k], a);
        ub[nl * 32 + f] = __float2half_rn(a * ldinv[nl]);
    }
}

// gather 8 rows (sA,sB) as uint4 at lane q4 (4 lanes/row); 2-level packed
// fp16 pairwise tree per half2 word, explicit named temporaries (no pointer
// arithmetic over locals), convert+add into 8 f32 carries. Per-feature
// arithmetic order identical to the uint2 version.
#define GATHER8Q(uq, sA, sB, q4, a0, a1, a2, a3, a4, a5, a6, a7) \
    { uint4 _v0 = uq[(size_t)(sA).x * 4 + (q4)]; \
      uint4 _v1 = uq[(size_t)(sA).y * 4 + (q4)]; \
      uint4 _v2 = uq[(size_t)(sA).z * 4 + (q4)]; \
      uint4 _v3 = uq[(size_t)(sA).w * 4 + (q4)]; \
      uint4 _v4 = uq[(size_t)(sB).x * 4 + (q4)]; \
      uint4 _v5 = uq[(size_t)(sB).y * 4 + (q4)]; \
      uint4 _v6 = uq[(size_t)(sB).z * 4 + (q4)]; \
      uint4 _v7 = uq[(size_t)(sB).w * 4 + (q4)]; \
      __half2* _h0 = (__half2*)&_v0; __half2* _h1 = (__half2*)&_v1; \
      __half2* _h2 = (__half2*)&_v2; __half2* _h3 = (__half2*)&_v3; \
      __half2* _h4 = (__half2*)&_v4; __half2* _h5 = (__half2*)&_v5; \
      __half2* _h6 = (__half2*)&_v6; __half2* _h7 = (__half2*)&_v7; \
      __half2 _w0a = __hadd2(__hadd2(_h0[0], _h1[0]), __hadd2(_h2[0], _h3[0])); \
      __half2 _w0b = __hadd2(__hadd2(_h4[0], _h5[0]), __hadd2(_h6[0], _h7[0])); \
      __half2 _w1a = __hadd2(__hadd2(_h0[1], _h1[1]), __hadd2(_h2[1], _h3[1])); \
      __half2 _w1b = __hadd2(__hadd2(_h4[1], _h5[1]), __hadd2(_h6[1], _h7[1])); \
      __half2 _w2a = __hadd2(__hadd2(_h0[2], _h1[2]), __hadd2(_h2[2], _h3[2])); \
      __half2 _w2b = __hadd2(__hadd2(_h4[2], _h5[2]), __hadd2(_h6[2], _h7[2])); \
      __half2 _w3a = __hadd2(__hadd2(_h0[3], _h1[3]), __hadd2(_h2[3], _h3[3])); \
      __half2 _w3b = __hadd2(__hadd2(_h4[3], _h5[3]), __hadd2(_h6[3], _h7[3])); \
      float2 _f0a = __half22float2(_w0a), _f0b = __half22float2(_w0b); \
      float2 _f1a = __half22float2(_w1a), _f1b = __half22float2(_w1b); \
      float2 _f2a = __half22float2(_w2a), _f2b = __half22float2(_w2b); \
      float2 _f3a = __half22float2(_w3a), _f3b = __half22float2(_w3b); \
      a0 += _f0a.x + _f0b.x;  a1 += _f0a.y + _f0b.y; \
      a2 += _f1a.x + _f1b.x;  a3 += _f1a.y + _f1b.y; \
      a4 += _f2a.x + _f2b.x;  a5 += _f2a.y + _f2b.y; \
      a6 += _f3a.x + _f3b.x;  a7 += _f3a.y + _f3b.y; }

// fused layer1: 4 lanes/node x uint4, 16 nodes/wave, 8 rows/iter, csr
// prefetch -> elementwise relu/scale -> u2h fp16 rows.
__global__ void k_fused1(const uint4* __restrict__ u1q, const int* __restrict__ row_start,
                         const int* __restrict__ cnt8, const int* __restrict__ csr,
                         const float* __restrict__ dinv,
                         const float* __restrict__ b1, __half* __restrict__ u2h,
                         int n) {
    int t = threadIdx.x;
    int lane = t & 63, wv = t >> 6;
    int q4 = lane & 3, grp = lane >> 2;     // 16 nodes/wave
    int node = (blockIdx.x * 4 + wv) * 16 + grp;
    if (node >= n) return;
    const float4* b4 = (const float4*)b1;
    float4 bbA = b4[2 * q4], bbB = b4[2 * q4 + 1];
    uint4 sv = u1q[(size_t)node * 4 + q4];
    __half2* sh = (__half2*)&sv;
    float a0, a1, a2, a3, a4, a5, a6, a7;
    { float2 f0 = __half22float2(sh[0]), f1 = __half22float2(sh[1]);
      float2 f2 = __half22float2(sh[2]), f3 = __half22float2(sh[3]);
      a0 = f0.x; a1 = f0.y; a2 = f1.x; a3 = f1.y;
      a4 = f2.x; a5 = f2.y; a6 = f3.x; a7 = f3.y; }
    int beg = row_start[node];
    int it = cnt8[node];
    const int4* ip = (const int4*)(csr + beg);
    if (it > 0) {
        int4 sA = ip[0], sB = ip[1];
        for (int i = 0; i < it; ++i) {
            int4 nA = ip[2 * i + 2];          // 1-deep prefetch (slab slack)
            int4 nB = ip[2 * i + 3];
            GATHER8Q(u1q, sA, sB, q4, a0, a1, a2, a3, a4, a5, a6, a7)
            sA = nA; sB = nB;
        }
    }
    float di = dinv[node];
    float r0 = fmaxf(fmaf(di, a0, bbA.x), 0.f) * di;
    float r1 = fmaxf(fmaf(di, a1, bbA.y), 0.f) * di;
    float r2 = fmaxf(fmaf(di, a2, bbA.z), 0.f) * di;
    float r3 = fmaxf(fmaf(di, a3, bbA.w), 0.f) * di;
    float r4 = fmaxf(fmaf(di, a4, bbB.x), 0.f) * di;
    float r5 = fmaxf(fmaf(di, a5, bbB.y), 0.f) * di;
    float r6 = fmaxf(fmaf(di, a6, bbB.z), 0.f) * di;
    float r7 = fmaxf(fmaf(di, a7, bbB.w), 0.f) * di;
    uint4 st;
    __half2* sp = (__half2*)&st;
    sp[0].x = __float2half_rn(r0); sp[0].y = __float2half_rn(r1);
    sp[1].x = __float2half_rn(r2); sp[1].y = __float2half_rn(r3);
    sp[2].x = __float2half_rn(r4); sp[2].y = __float2half_rn(r5);
    sp[3].x = __float2half_rn(r6); sp[3].y = __float2half_rn(r7);
    ((uint4*)u2h)[(size_t)node * 4 + q4] = st;
}

// fused layer2 + head: 4 lanes/node x uint4, 16 nodes/wave -> intra-wave LDS
// -> transform (lane = output o, W2 col loaded after agg) -> FC butterfly ->
// log_softmax.
__global__ void k_fused2(const uint4* __restrict__ u2q, const int* __restrict__ row_start,
                         const int* __restrict__ cnt8, const int* __restrict__ csr,
                         const float* __restrict__ dinv,
                         const float* __restrict__ W2,
                         const float* __restrict__ b2, const float* __restrict__ Wfc,
                         const float* __restrict__ bfc, float* __restrict__ out,
                         int n) {
    __shared__ float lagg[4][16][33];
    int t = threadIdx.x;
    int lane = t & 63, wv = t >> 6;
    int q4 = lane & 3, grp = lane >> 2;     // 16 nodes/wave
    int node0 = (blockIdx.x * 4 + wv) * 16;
    int node = node0 + grp;
    float a0 = 0.f, a1 = 0.f, a2 = 0.f, a3 = 0.f;
    float a4 = 0.f, a5 = 0.f, a6 = 0.f, a7 = 0.f;
    if (node < n) {
        uint4 sv = u2q[(size_t)node * 4 + q4];
        __half2* sh = (__half2*)&sv;
        float2 f0 = __half22float2(sh[0]), f1 = __half22float2(sh[1]);
        float2 f2 = __half22float2(sh[2]), f3 = __half22float2(sh[3]);
        a0 = f0.x; a1 = f0.y; a2 = f1.x; a3 = f1.y;
        a4 = f2.x; a5 = f2.y; a6 = f3.x; a7 = f3.y;
        int beg = row_start[node];
        int it = cnt8[node];
        const int4* ip = (const int4*)(csr + beg);
        if (it > 0) {
            int4 sA = ip[0], sB = ip[1];
            for (int i = 0; i < it; ++i) {
                int4 nA = ip[2 * i + 2];      // 1-deep prefetch
                int4 nB = ip[2 * i + 3];
                GATHER8Q(u2q, sA, sB, q4, a0, a1, a2, a3, a4, a5, a6, a7)
                sA = nA; sB = nB;
            }
        }
    }
    int fb = q4 * 8;
    lagg[wv][grp][fb + 0] = a0; lagg[wv][grp][fb + 1] = a1;
    lagg[wv][grp][fb + 2] = a2; lagg[wv][grp][fb + 3] = a3;
    lagg[wv][grp][fb + 4] = a4; lagg[wv][grp][fb + 5] = a5;
    lagg[wv][grp][fb + 6] = a6; lagg[wv][grp][fb + 7] = a7;
    // intra-wave handoff (same wave produces and consumes; DS in-order)
    float w2r[32];
#pragma unroll
    for (int k = 0; k < 32; ++k) w2r[k] = W2[k * 64 + lane];
    float b2v = b2[lane];
    float wf0 = Wfc[lane * 2 + 0], wf1 = Wfc[lane * 2 + 1];
    float bf0 = bfc[0], bf1 = bfc[1];
#pragma unroll
    for (int r = 0; r < 16; ++r) {
        int nodeT = node0 + r;
        const float* rp = lagg[wv][r];
        float c0 = 0.f, c1 = 0.f, c2 = 0.f, c3 = 0.f;
#pragma unroll
        for (int k = 0; k < 32; k += 4) {
            c0 = fmaf(rp[k],     w2r[k],     c0);
            c1 = fmaf(rp[k + 1], w2r[k + 1], c1);
            c2 = fmaf(rp[k + 2], w2r[k + 2], c2);
            c3 = fmaf(rp[k + 3], w2r[k + 3], c3);
        }
        float a = (c0 + c1) + (c2 + c3);
        float v = (nodeT < n) ? fmaxf(fmaf(dinv[nodeT], a, b2v), 0.f) : 0.f;
        float l0 = v * wf0;
        float l1 = v * wf1;
#pragma unroll
        for (int off = 32; off >= 1; off >>= 1) {
            l0 += __shfl_xor(l0, off, 64);
            l1 += __shfl_xor(l1, off, 64);
        }
        if (lane == 0 && nodeT < n) {
            l0 += bf0;
            l1 += bf1;
            float m2 = fmaxf(l0, l1);
            float lse = m2 + __logf(__expf(l0 - m2) + __expf(l1 - m2));
            out[nodeT * 2 + 0] = l0 - lse;
            out[nodeT * 2 + 1] = l1 - lse;
        }
    }
}

extern "C" void kernel_launch(void* const* d_in, const int* in_sizes, int n_in,
                              void* d_out, int out_size, void* d_ws, size_t ws_size,
                              hipStream_t stream) {
    const float* x   = (const float*)d_in[0];
    const int*   ei  = (const int*)d_in[1];
    const float* W1  = (const float*)d_in[2];
    const float* b1  = (const float*)d_in[3];
    const float* W2  = (const float*)d_in[4];
    const float* b2  = (const float*)d_in[5];
    const float* Wfc = (const float*)d_in[6];
    const float* bfc = (const float*)d_in[7];
    float* out = (float*)d_out;

    const int n = in_sizes[0] / 18;
    const int E = in_sizes[1] / 2;
    const int* src = ei;
    const int* dst = ei + E;
    const int nbuck = (n + BNODES - 1) >> BSH;

    // ws: bcursor[nbuck] | row_start[n] | cnt8[n] | dinv[n]
    //  | eb[nbuck*CAP] | csr[nbuck*CAP]+slack | u1h[(n+1)*32 h] | u2h[(n+1)*32 h]
    char* w = (char*)d_ws;
    int*    bcursor   = (int*)w;     w += (size_t)nbuck * 4;
    int*    row_start = (int*)w;     w += (size_t)n * 4;
    int*    cnt8      = (int*)w;     w += (size_t)n * 4;
    float*  dinv      = (float*)w;   w += (size_t)n * 4;
    int*    eb        = (int*)w;     w += (size_t)nbuck * CAP * 4;
    int*    csr       = (int*)w;     w += (size_t)nbuck * CAP * 4 + 128; // +prefetch slack
    w = (char*)(((size_t)w + 63) & ~(size_t)63);
    __half* u1h       = (__half*)w;  w += (size_t)(n + 1) * 32 * 2;
    w = (char*)(((size_t)w + 63) & ~(size_t)63);
    __half* u2h       = (__half*)w;  w += (size_t)(n + 1) * 32 * 2;

    // ---- CSR build: slab bucket sort with padded segments ----
    hipMemsetAsync(bcursor, 0, (size_t)nbuck * 4, stream);
    k_part<<<(E + CH - 1) / CH, TPB, 0, stream>>>(src, dst, bcursor, eb, u1h, u2h, E, n, nbuck);
    k_bucket<<<nbuck, TPB, 0, stream>>>(eb, bcursor, x, W1, csr, row_start, cnt8,
                                        dinv, u1h, n);

    const int waves = (n + 15) / 16;        // 16 nodes/wave
    const int blocksF = (waves + 3) / 4;

    k_fused1<<<blocksF, TPB, 0, stream>>>((const uint4*)u1h, row_start, cnt8, csr,
                                          dinv, b1, u2h, n);
    k_fused2<<<blocksF, TPB, 0, stream>>>((const uint4*)u2h, row_start, cnt8, csr,
                                          dinv, W2, b2, Wfc, bfc, out, n);
}